// Round 3
// baseline (561.006 us; speedup 1.0000x reference)
//
#include <hip/hip_runtime.h>
#include <hip/hip_bf16.h>

#define N_    64
#define CIN   64
#define COUT  64
#define T_    256
#define V_    25
#define K_    3
#define G_    8
#define D_    192          // K_*COUT
#define TV    6400         // T_*V_
#define P_    409600.0f    // N_*T_*V_

__device__ __forceinline__ float bf2f(unsigned short u) {
    unsigned int x = ((unsigned int)u) << 16;
    return __uint_as_float(x);
}
__device__ __forceinline__ unsigned short f2bf(float f) {
    unsigned int x = __float_as_uint(f);
    unsigned int lsb = (x >> 16) & 1u;
    x += 0x7fffu + lsb;                 // round-to-nearest-even (no NaN/inf in this problem)
    return (unsigned short)(x >> 16);
}

// K1: y[n,d,t,v] = sum_c x0[n,c,t,v] * W[c,d] + bias[d]   (stored bf16)
__global__ __launch_bounds__(256) void k1_gemm(const float* __restrict__ x0,
                                               const float* __restrict__ W,
                                               const float* __restrict__ bias,
                                               unsigned short* __restrict__ y) {
    const int nblk = TV / 256;                 // 25
    int n  = blockIdx.x / nblk;
    int q  = (blockIdx.x % nblk) * 256 + threadIdx.x;
    const float* xp = x0 + (size_t)n * CIN * TV + q;
    float x[CIN];
#pragma unroll
    for (int c = 0; c < CIN; ++c) x[c] = xp[(size_t)c * TV];
    unsigned short* yp = y + (size_t)n * D_ * TV + q;
    for (int d0 = 0; d0 < D_; d0 += 16) {
        float acc[16];
#pragma unroll
        for (int j = 0; j < 16; ++j) acc[j] = bias[d0 + j];
#pragma unroll
        for (int c = 0; c < CIN; ++c) {
            float xc = x[c];
#pragma unroll
            for (int j = 0; j < 16; ++j) acc[j] += xc * W[c * D_ + d0 + j];
        }
#pragma unroll
        for (int j = 0; j < 16; ++j) yp[(size_t)(d0 + j) * TV] = f2bf(acc[j]);
    }
}

// K1b: per-channel (192) sum / sumsq of y over all N*T*V positions.
__global__ __launch_bounds__(256) void k1b_stats(const unsigned short* __restrict__ y,
                                                 float* __restrict__ sum0,
                                                 float* __restrict__ sumsq0) {
    int d    = blockIdx.x;      // 0..191
    int slab = blockIdx.y;      // 0..7
    float s = 0.f, sq = 0.f;
    for (int n = slab * 8; n < slab * 8 + 8; ++n) {
        const ushort4* yp = (const ushort4*)(y + ((size_t)n * D_ + d) * TV);
        for (int i = threadIdx.x; i < TV / 4; i += 256) {
            ushort4 u = yp[i];
            float a0 = bf2f(u.x), a1 = bf2f(u.y), a2 = bf2f(u.z), a3 = bf2f(u.w);
            s  += (a0 + a1) + (a2 + a3);
            sq += (a0 * a0 + a1 * a1) + (a2 * a2 + a3 * a3);
        }
    }
    __shared__ float rs[256], rq[256];
    rs[threadIdx.x] = s; rq[threadIdx.x] = sq;
    __syncthreads();
    for (int off = 128; off > 0; off >>= 1) {
        if (threadIdx.x < off) {
            rs[threadIdx.x] += rs[threadIdx.x + off];
            rq[threadIdx.x] += rq[threadIdx.x + off];
        }
        __syncthreads();
    }
    if (threadIdx.x == 0) {
        atomicAdd(&sum0[d], rs[0]);
        atomicAdd(&sumsq0[d], rq[0]);
    }
}

// K2 (1 block): BN0 affine (a,b), column-normalized adjacency, bconst[c][w].
__global__ __launch_bounds__(256) void k2_prep(const float* __restrict__ A,
                                               const float* __restrict__ g0,
                                               const float* __restrict__ b0,
                                               const float* __restrict__ sum0,
                                               const float* __restrict__ sumsq0,
                                               float* a, float* b,
                                               float* nadj, float* bconst) {
    int tid = threadIdx.x;
    if (tid < D_) {
        float m   = sum0[tid] / P_;
        float var = sumsq0[tid] / P_ - m * m;
        float sc  = g0[tid] * rsqrtf(var + 1e-5f);
        a[tid] = sc;
        b[tid] = b0[tid] - sc * m;
    }
    // nadj[k,g,v,w] = A[k,g,v,w] / (colsum_v + 1e-3)
    for (int idx = tid; idx < K_ * G_ * V_; idx += 256) {
        int w  = idx % V_;
        int kg = idx / V_;
        const float* Ap = A + kg * V_ * V_;
        float cs = 0.f;
        for (int v = 0; v < V_; ++v) cs += Ap[v * V_ + w];
        float inv = 1.f / (cs + 1e-3f);
        for (int v = 0; v < V_; ++v) nadj[kg * V_ * V_ + v * V_ + w] = Ap[v * V_ + w] * inv;
    }
    __syncthreads();
    // bconst[c,w] = sum_k b[k*64+c] * sum_v nadj[k, c%8, v, w]
    for (int idx = tid; idx < COUT * V_; idx += 256) {
        int c = idx / V_, w = idx % V_, g = c & 7;
        float s = 0.f;
        for (int k = 0; k < K_; ++k) {
            float bk = b[k * COUT + c];
            const float* np_ = nadj + (k * G_ + g) * V_ * V_;
            float cs = 0.f;
            for (int v = 0; v < V_; ++v) cs += np_[v * V_ + w];
            s += bk * cs;
        }
        bconst[idx] = s;
    }
}

// K3: x2[n,c,t,w] = bconst[c,w] + sum_{k,v} a[k*64+c]*y[n,k*64+c,t,v]*nadj[k,c%8,v,w]
// block = (n,c); thread = t. Fused BN2 stats.
__global__ __launch_bounds__(256) void k3_adj(const unsigned short* __restrict__ y,
                                              const float* __restrict__ a,
                                              const float* __restrict__ nadj,
                                              const float* __restrict__ bconst,
                                              unsigned short* __restrict__ x2,
                                              float* __restrict__ sum2,
                                              float* __restrict__ sumsq2) {
    int n = blockIdx.x >> 6;
    int c = blockIdx.x & 63;
    int g = c & 7;
    __shared__ float s_nadj[K_][V_ * V_];
    for (int idx = threadIdx.x; idx < K_ * V_ * V_; idx += 256) {
        int k = idx / (V_ * V_), r = idx % (V_ * V_);
        s_nadj[k][r] = nadj[(k * G_ + g) * (V_ * V_) + r];
    }
    __syncthreads();
    int t = threadIdx.x;
    float acc[V_];
    const float* bc = bconst + c * V_;
#pragma unroll
    for (int w = 0; w < V_; ++w) acc[w] = bc[w];
#pragma unroll
    for (int k = 0; k < K_; ++k) {
        float ak = a[k * COUT + c];
        const unsigned short* yp = y + ((size_t)n * D_ + k * COUT + c) * TV + t * V_;
        float yv[V_];
#pragma unroll
        for (int v = 0; v < V_; ++v) yv[v] = ak * bf2f(yp[v]);
#pragma unroll
        for (int v = 0; v < V_; ++v) {
            float yk = yv[v];
            const float* np_ = &s_nadj[k][v * V_];
#pragma unroll
            for (int w = 0; w < V_; ++w) acc[w] += yk * np_[w];
        }
    }
    unsigned short* xp = x2 + ((size_t)n * COUT + c) * TV + t * V_;
    float s = 0.f, sq = 0.f;
#pragma unroll
    for (int w = 0; w < V_; ++w) {
        float v = acc[w];
        s += v; sq += v * v;
        xp[w] = f2bf(v);
    }
    __shared__ float rs[256], rq[256];
    rs[t] = s; rq[t] = sq;
    __syncthreads();
    for (int off = 128; off > 0; off >>= 1) {
        if (t < off) { rs[t] += rs[t + off]; rq[t] += rq[t + off]; }
        __syncthreads();
    }
    if (t == 0) {
        atomicAdd(&sum2[c], rs[0]);
        atomicAdd(&sumsq2[c], rq[0]);
    }
}

// K4: out = relu(BN2(x2) + x0), FLOAT32 out (reference output dtype is f32).
__global__ __launch_bounds__(256) void k4_final(const unsigned short* __restrict__ x2,
                                                const float* __restrict__ x0,
                                                const float* __restrict__ g2,
                                                const float* __restrict__ b2,
                                                const float* __restrict__ sum2,
                                                const float* __restrict__ sumsq2,
                                                float* __restrict__ out) {
    const int total4 = N_ * COUT * TV / 4;
    for (int i = blockIdx.x * 256 + threadIdx.x; i < total4; i += gridDim.x * 256) {
        int c = ((i * 4) / TV) & 63;
        float m   = sum2[c] * (1.f / P_);
        float var = sumsq2[c] * (1.f / P_) - m * m;
        float sc  = g2[c] * rsqrtf(var + 1e-5f);
        float sh  = b2[c] - sc * m;
        ushort4 u = ((const ushort4*)x2)[i];
        float4  x = ((const float4*)x0)[i];
        float4 o;
        o.x = fmaxf(sc * bf2f(u.x) + sh + x.x, 0.f);
        o.y = fmaxf(sc * bf2f(u.y) + sh + x.y, 0.f);
        o.z = fmaxf(sc * bf2f(u.z) + sh + x.z, 0.f);
        o.w = fmaxf(sc * bf2f(u.w) + sh + x.w, 0.f);
        ((float4*)out)[i] = o;
    }
}

extern "C" void kernel_launch(void* const* d_in, const int* in_sizes, int n_in,
                              void* d_out, int out_size, void* d_ws, size_t ws_size,
                              hipStream_t stream) {
    const float* x0   = (const float*)d_in[0];
    const float* A    = (const float*)d_in[1];
    const float* W    = (const float*)d_in[2];
    const float* bias = (const float*)d_in[3];
    const float* g0   = (const float*)d_in[4];
    const float* b0   = (const float*)d_in[5];
    const float* g2   = (const float*)d_in[6];
    const float* b2   = (const float*)d_in[7];

    char* ws = (char*)d_ws;
    unsigned short* y  = (unsigned short*)ws;                       // 157,286,400 B
    unsigned short* x2 = (unsigned short*)(ws + 157286400ull);      //  52,428,800 B
    float* fregion = (float*)(ws + 209715200ull);
    float* sum0   = fregion;          // 192
    float* sumsq0 = fregion + 192;    // 192
    float* sum2   = fregion + 384;    // 64
    float* sumsq2 = fregion + 448;    // 64   -> 512 floats to zero
    float* a      = fregion + 512;    // 192
    float* b      = a + 192;          // 192
    float* nadj   = b + 192;          // 15000
    float* bconst = nadj + 15000;     // 1600

    hipMemsetAsync(fregion, 0, 512 * sizeof(float), stream);
    k1_gemm<<<N_ * (TV / 256), 256, 0, stream>>>(x0, W, bias, y);
    k1b_stats<<<dim3(D_, 8), 256, 0, stream>>>(y, sum0, sumsq0);
    k2_prep<<<1, 256, 0, stream>>>(A, g0, b0, sum0, sumsq0, a, b, nadj, bconst);
    k3_adj<<<N_ * COUT, 256, 0, stream>>>(y, a, nadj, bconst, x2, sum2, sumsq2);
    k4_final<<<2048, 256, 0, stream>>>(x2, x0, g2, b2, sum2, sumsq2,
                                       (float*)d_out);
}